// Round 1
// baseline (401.077 us; speedup 1.0000x reference)
//
#include <hip/hip_runtime.h>
#include <math.h>

typedef unsigned short u16;
typedef unsigned int   u32;
typedef __attribute__((ext_vector_type(8))) short  short8;
typedef __attribute__((ext_vector_type(4))) float  floatx4;

#define Bn  32
#define Cn  256
#define HWn 3136
#define Gn  4
#define CRn 64

__device__ __forceinline__ float gelu_f(float x) {
    return 0.5f * x * (1.0f + erff(x * 0.70710678118654752f));
}
// fp32 -> bf16 bits, round-to-nearest-even
__device__ __forceinline__ u16 f2bf(float f) {
    u32 u = __builtin_bit_cast(u32, f);
    u = (u + 0x7fffu + ((u >> 16) & 1u)) >> 16;
    return (u16)u;
}

// ---------------------------------------------------------------------------
// Kernel 1: mean-pool r over HW (blocks 0..8191) + convert pw_w to bf16
// (blocks 8192..8255).
// ---------------------------------------------------------------------------
__global__ __launch_bounds__(256) void k_pool(const float* __restrict__ r,
                                              const float* __restrict__ pw_w,
                                              float* __restrict__ pooled,
                                              u16* __restrict__ wbf) {
    int blk = blockIdx.x, t = threadIdx.x;
    if (blk >= Bn * Cn) {
        int base = (blk - Bn * Cn) * 1024 + t;
        #pragma unroll
        for (int i = 0; i < 4; i++) wbf[base + i * 256] = f2bf(pw_w[base + i * 256]);
        return;
    }
    const float4* src = (const float4*)(r + (size_t)blk * HWn);
    float sum = 0.f;
    for (int i = t; i < HWn / 4; i += 256) {
        float4 v = src[i];
        sum += (v.x + v.y) + (v.z + v.w);
    }
    #pragma unroll
    for (int off = 32; off >= 1; off >>= 1) sum += __shfl_down(sum, off, 64);
    __shared__ float red[4];
    if ((t & 63) == 0) red[t >> 6] = sum;
    __syncthreads();
    if (t == 0) pooled[blk] = (red[0] + red[1] + red[2] + red[3]) * (1.0f / 3136.0f);
}

// ---------------------------------------------------------------------------
// Kernel 2: SE weight generation. One block per batch b (32 blocks).
// pooled[b] -> h(64) -> scale(2048) -> alpha/beta -> wk[b][c][49]
// ---------------------------------------------------------------------------
__global__ __launch_bounds__(256) void k_wgen(const float* __restrict__ pooled,
                                              const float* __restrict__ w1,
                                              const float* __restrict__ b1,
                                              const float* __restrict__ w2,
                                              const float* __restrict__ b2,
                                              const float* __restrict__ weight,
                                              const float* __restrict__ beta_scale,
                                              float* __restrict__ wk) {
    int b = blockIdx.x, t = threadIdx.x;
    __shared__ float sp[Cn];
    __shared__ float sh[CRn];
    __shared__ float ssc[Cn * Gn * 2];
    sp[t] = pooled[b * Cn + t];
    __syncthreads();
    if (t < CRn) {
        float acc = b1[t];
        const float* wr = w1 + t * Cn;
        for (int c = 0; c < Cn; c++) acc += sp[c] * wr[c];
        sh[t] = gelu_f(acc);
    }
    __syncthreads();
    for (int i = t; i < Cn * Gn * 2; i += 256) {
        float acc = b2[i];
        const float* wr = w2 + i * CRn;
        #pragma unroll 8
        for (int j = 0; j < CRn; j++) acc += sh[j] * wr[j];
        ssc[i] = acc;
    }
    __syncthreads();
    // thread t handles channel c = t
    float av[Gn], bt[Gn];
    float mx = -1e30f;
    #pragma unroll
    for (int g = 0; g < Gn; g++) {
        av[g] = ssc[(g * Cn + t) * 2 + 0];
        float s1 = ssc[(g * Cn + t) * 2 + 1];
        bt[g] = tanhf(s1 * expf(beta_scale[g * Cn + t]) * 0.1f);
        mx = fmaxf(mx, av[g]);
    }
    float se = 0.f;
    #pragma unroll
    for (int g = 0; g < Gn; g++) { av[g] = expf(av[g] - mx); se += av[g]; }
    float inv = 1.0f / se;
    #pragma unroll
    for (int g = 0; g < Gn; g++) av[g] *= inv;
    float bsum = bt[0] + bt[1] + bt[2] + bt[3];
    float* out = wk + ((size_t)b * Cn + t) * 49;
    for (int kk = 0; kk < 49; kk++) {
        float w = bsum;
        #pragma unroll
        for (int g = 0; g < Gn; g++) w += av[g] * weight[(g * Cn + t) * 49 + kk];
        out[kk] = w;
    }
}

// ---------------------------------------------------------------------------
// Kernel 3: depthwise 7x7 conv (pad 3) + exact gelu -> bf16 X in [b][c][hw].
// One block per (b,c). 62x62 zero-padded channel in LDS; threads 0..195
// each compute a 4x4 register tile (6.25 LDS reads / output).
// ---------------------------------------------------------------------------
__global__ __launch_bounds__(256) void k_dw(const float* __restrict__ s,
                                            const float* __restrict__ wk,
                                            u16* __restrict__ xdw) {
    int bc = blockIdx.x, t = threadIdx.x;
    __shared__ float kw[49];
    __shared__ float sin_[62 * 62];
    for (int i = t; i < 62 * 62; i += 256) sin_[i] = 0.f;
    if (t < 49) kw[t] = wk[(size_t)bc * 49 + t];
    __syncthreads();
    const float4* src = (const float4*)(s + (size_t)bc * HWn);
    for (int i = t; i < HWn / 4; i += 256) {
        float4 v = src[i];
        int row = i / 14;
        int col = (i % 14) * 4;
        float* dst = &sin_[(row + 3) * 62 + col + 3];
        dst[0] = v.x; dst[1] = v.y; dst[2] = v.z; dst[3] = v.w;
    }
    __syncthreads();
    if (t < 196) {
        int r0 = (t / 14) * 4, c0 = (t % 14) * 4;
        float acc[4][4] = {};
        #pragma unroll
        for (int a = 0; a < 10; a++) {
            float row10[10];
            const float* rp = &sin_[(r0 + a) * 62 + c0];
            #pragma unroll
            for (int x = 0; x < 10; x++) row10[x] = rp[x];
            #pragma unroll
            for (int i = 0; i < 4; i++) {
                int ky = a - i;                       // compile-time after unroll
                if (ky >= 0 && ky < 7) {
                    #pragma unroll
                    for (int kx = 0; kx < 7; kx++) {
                        float wv = kw[ky * 7 + kx];
                        #pragma unroll
                        for (int j = 0; j < 4; j++) acc[i][j] += row10[j + kx] * wv;
                    }
                }
            }
        }
        u16* dst = xdw + (size_t)bc * HWn;
        #pragma unroll
        for (int i = 0; i < 4; i++) {
            u16 ov[4];
            #pragma unroll
            for (int j = 0; j < 4; j++) ov[j] = f2bf(gelu_f(acc[i][j]));
            *(uint2*)(dst + (r0 + i) * 56 + c0) = *(const uint2*)ov;
        }
    }
}

// ---------------------------------------------------------------------------
// Kernel 4: pointwise GEMM, bf16 MFMA 16x16x32, fp32 out + bias.
// Per b: Out[256 d][3136 hw] = W[256][256] * X[256 c][3136 hw].
// Block tile 128d x 128hw, 4 waves (2x2), wave tile 64x64, BK=32, 8 k-steps.
// X staged TRANSPOSED in LDS ([hw][c], stride 40, xor-swizzled c-groups) so
// both A and B fragments are ds_read_b128.
// ---------------------------------------------------------------------------
__global__ __launch_bounds__(256) void k_pw(const u16* __restrict__ xdw,
                                            const u16* __restrict__ wbf,
                                            const float* __restrict__ pw_b,
                                            float* __restrict__ out) {
    int tileHW = blockIdx.x;      // 0..24  (3136 = 24*128 + 64)
    int tileD  = blockIdx.y;      // 0..1
    int b      = blockIdx.z;      // 0..31
    int t = threadIdx.x;
    int lane = t & 63;
    int wv = t >> 6;
    int waveM = wv >> 1, waveN = wv & 1;
    int hw0 = tileHW * 128;
    int d0  = tileD * 128;

    __shared__ __align__(16) u16 sA[128 * 40];   // [d][k]  stride 40
    __shared__ __align__(16) u16 sX[128 * 40];   // [hw][c] stride 40, swizzled

    floatx4 acc[4][4];
    #pragma unroll
    for (int mi = 0; mi < 4; mi++)
        #pragma unroll
        for (int ni = 0; ni < 4; ni++) acc[mi][ni] = (floatx4){0.f, 0.f, 0.f, 0.f};

    int arow = t >> 2;            // 0..63
    int akc  = t & 3;             // 0..3 (k-chunk of 8)
    int xc   = t >> 3;            // 0..31 (channel within k-step)
    int xhc  = t & 7;             // 0..7  (hw chunk of 8)
    int wgrp = (xc >> 3) ^ (xhc & 3);
    int scol = (wgrp << 3) | (xc & 7);

    const u16* Xbase = xdw + (size_t)b * Cn * HWn;
    int q = lane >> 4, l16 = lane & 15;

    for (int ks = 0; ks < 8; ks++) {
        int k0 = ks * 32;
        __syncthreads();
        // stage A (W tile)
        #pragma unroll
        for (int half = 0; half < 2; half++) {
            int dd = arow + half * 64;
            short8 v = *(const short8*)(wbf + (d0 + dd) * 256 + k0 + akc * 8);
            *(short8*)(&sA[dd * 40 + akc * 8]) = v;
        }
        // stage X transposed
        #pragma unroll
        for (int half = 0; half < 2; half++) {
            int colb = xhc * 8 + half * 64;
            int hw = hw0 + colb;
            short8 v = short8{0, 0, 0, 0, 0, 0, 0, 0};
            if (hw < HWn) v = *(const short8*)(Xbase + (size_t)(k0 + xc) * HWn + hw);
            const u16* vp = (const u16*)&v;
            #pragma unroll
            for (int e = 0; e < 8; e++) sX[(colb + e) * 40 + scol] = vp[e];
        }
        __syncthreads();
        short8 fa[4], fb[4];
        #pragma unroll
        for (int mi = 0; mi < 4; mi++) {
            int row = waveM * 64 + mi * 16 + l16;
            fa[mi] = *(const short8*)(&sA[row * 40 + q * 8]);
        }
        #pragma unroll
        for (int ni = 0; ni < 4; ni++) {
            int hwRow = waveN * 64 + ni * 16 + l16;
            int rgrp = q ^ ((hwRow >> 3) & 3);
            fb[ni] = *(const short8*)(&sX[hwRow * 40 + rgrp * 8]);
        }
        #pragma unroll
        for (int mi = 0; mi < 4; mi++)
            #pragma unroll
            for (int ni = 0; ni < 4; ni++)
                acc[mi][ni] = __builtin_amdgcn_mfma_f32_16x16x32_bf16(fa[mi], fb[ni], acc[mi][ni], 0, 0, 0);
    }
    // epilogue: D row = q*4+reg (d), col = l16 (hw)
    #pragma unroll
    for (int mi = 0; mi < 4; mi++) {
        #pragma unroll
        for (int reg = 0; reg < 4; reg++) {
            int d = d0 + waveM * 64 + mi * 16 + q * 4 + reg;
            float bias = pw_b[d];
            #pragma unroll
            for (int ni = 0; ni < 4; ni++) {
                int hw = hw0 + waveN * 64 + ni * 16 + l16;
                if (hw < HWn)
                    out[((size_t)b * Cn + d) * HWn + hw] = acc[mi][ni][reg] + bias;
            }
        }
    }
}

// ---------------------------------------------------------------------------
extern "C" void kernel_launch(void* const* d_in, const int* in_sizes, int n_in,
                              void* d_out, int out_size, void* d_ws, size_t ws_size,
                              hipStream_t stream) {
    const float* s          = (const float*)d_in[0];
    const float* r          = (const float*)d_in[1];
    const float* proj_w1    = (const float*)d_in[2];
    const float* proj_b1    = (const float*)d_in[3];
    const float* proj_w2    = (const float*)d_in[4];
    const float* proj_b2    = (const float*)d_in[5];
    const float* weight     = (const float*)d_in[6];
    const float* beta_scale = (const float*)d_in[7];
    const float* pw_w       = (const float*)d_in[8];
    const float* pw_b       = (const float*)d_in[9];
    float* out = (float*)d_out;

    char* ws = (char*)d_ws;
    float* pooled = (float*)(ws);                    //  32 KB
    u16*   wbf    = (u16*)(ws + 32768);              // 128 KB
    float* wk     = (float*)(ws + 163840);           // 1.57 MB
    u16*   xdw    = (u16*)(ws + 2097152);            // 51.4 MB

    k_pool<<<Bn * Cn + 64, 256, 0, stream>>>(r, pw_w, pooled, wbf);
    k_wgen<<<Bn, 256, 0, stream>>>(pooled, proj_w1, proj_b1, proj_w2, proj_b2,
                                   weight, beta_scale, wk);
    k_dw<<<Bn * Cn, 256, 0, stream>>>(s, wk, xdw);
    k_pw<<<dim3(25, 2, Bn), 256, 0, stream>>>(xdw, wbf, pw_b, out);
}

// Round 2
// 365.380 us; speedup vs baseline: 1.0977x; 1.0977x over previous
//
#include <hip/hip_runtime.h>
#include <math.h>

typedef unsigned short u16;
typedef unsigned int   u32;
typedef __attribute__((ext_vector_type(8))) short  short8;
typedef __attribute__((ext_vector_type(4))) float  floatx4;

#define Bn  32
#define Cn  256
#define HWn 3136
#define Gn  4
#define CRn 64

__device__ __forceinline__ float gelu_f(float x) {
    return 0.5f * x * (1.0f + erff(x * 0.70710678118654752f));
}
// fast exact-form gelu: A&S 7.1.26 erf approx, |err_erf| <= 1.5e-7
__device__ __forceinline__ float gelu_fast(float x) {
    float ax = fabsf(x);
    float y  = ax * 0.70710678118654752f;
    float t  = __builtin_amdgcn_rcpf(fmaf(0.3275911f, y, 1.0f));
    float p  = fmaf(fmaf(fmaf(fmaf(1.061405429f, t, -1.453152027f), t,
                              1.421413741f), t, -0.284496736f), t, 0.254829592f) * t;
    float e  = __builtin_amdgcn_exp2f(-y * y * 1.442695040888963f);
    float er = fmaf(-p, e, 1.0f);            // erf(|x|/sqrt2)
    return fmaf(0.5f * ax, er, 0.5f * x);    // 0.5x + 0.5|x|erf(|x|/sqrt2)
}
// fp32 -> bf16 bits, round-to-nearest-even
__device__ __forceinline__ u16 f2bf(float f) {
    u32 u = __builtin_bit_cast(u32, f);
    u = (u + 0x7fffu + ((u >> 16) & 1u)) >> 16;
    return (u16)u;
}

// ---------------------------------------------------------------------------
// Kernel 1: mean-pool r over HW (blocks 0..8191) + convert pw_w to bf16
// (blocks 8192..8255).
// ---------------------------------------------------------------------------
__global__ __launch_bounds__(256) void k_pool(const float* __restrict__ r,
                                              const float* __restrict__ pw_w,
                                              float* __restrict__ pooled,
                                              u16* __restrict__ wbf) {
    int blk = blockIdx.x, t = threadIdx.x;
    if (blk >= Bn * Cn) {
        int base = (blk - Bn * Cn) * 1024 + t;
        #pragma unroll
        for (int i = 0; i < 4; i++) wbf[base + i * 256] = f2bf(pw_w[base + i * 256]);
        return;
    }
    const float4* src = (const float4*)(r + (size_t)blk * HWn);
    float sum = 0.f;
    for (int i = t; i < HWn / 4; i += 256) {
        float4 v = src[i];
        sum += (v.x + v.y) + (v.z + v.w);
    }
    #pragma unroll
    for (int off = 32; off >= 1; off >>= 1) sum += __shfl_down(sum, off, 64);
    __shared__ float red[4];
    if ((t & 63) == 0) red[t >> 6] = sum;
    __syncthreads();
    if (t == 0) pooled[blk] = (red[0] + red[1] + red[2] + red[3]) * (1.0f / 3136.0f);
}

// ---------------------------------------------------------------------------
// Kernel 2: SE weight generation. One block per batch b (32 blocks).
// ---------------------------------------------------------------------------
__global__ __launch_bounds__(256) void k_wgen(const float* __restrict__ pooled,
                                              const float* __restrict__ w1,
                                              const float* __restrict__ b1,
                                              const float* __restrict__ w2,
                                              const float* __restrict__ b2,
                                              const float* __restrict__ weight,
                                              const float* __restrict__ beta_scale,
                                              float* __restrict__ wk) {
    int b = blockIdx.x, t = threadIdx.x;
    __shared__ float sp[Cn];
    __shared__ float sh[CRn];
    __shared__ float ssc[Cn * Gn * 2];
    sp[t] = pooled[b * Cn + t];
    __syncthreads();
    if (t < CRn) {
        float acc = b1[t];
        const float* wr = w1 + t * Cn;
        for (int c = 0; c < Cn; c++) acc += sp[c] * wr[c];
        sh[t] = gelu_f(acc);
    }
    __syncthreads();
    for (int i = t; i < Cn * Gn * 2; i += 256) {
        float acc = b2[i];
        const float* wr = w2 + i * CRn;
        #pragma unroll 8
        for (int j = 0; j < CRn; j++) acc += sh[j] * wr[j];
        ssc[i] = acc;
    }
    __syncthreads();
    float av[Gn], bt[Gn];
    float mx = -1e30f;
    #pragma unroll
    for (int g = 0; g < Gn; g++) {
        av[g] = ssc[(g * Cn + t) * 2 + 0];
        float s1 = ssc[(g * Cn + t) * 2 + 1];
        bt[g] = tanhf(s1 * expf(beta_scale[g * Cn + t]) * 0.1f);
        mx = fmaxf(mx, av[g]);
    }
    float se = 0.f;
    #pragma unroll
    for (int g = 0; g < Gn; g++) { av[g] = expf(av[g] - mx); se += av[g]; }
    float inv = 1.0f / se;
    #pragma unroll
    for (int g = 0; g < Gn; g++) av[g] *= inv;
    float bsum = bt[0] + bt[1] + bt[2] + bt[3];
    float* out = wk + ((size_t)b * Cn + t) * 49;
    for (int kk = 0; kk < 49; kk++) {
        float w = bsum;
        #pragma unroll
        for (int g = 0; g < Gn; g++) w += av[g] * weight[(g * Cn + t) * 49 + kk];
        out[kk] = w;
    }
}

// ---------------------------------------------------------------------------
// Kernel 3: depthwise 7x7 conv (pad 3) + fast exact gelu -> bf16 X [b][c][hw].
// One block (128 thr) per (b,c). 62x62 zero-padded channel in LDS.
// Threads 0..111 each compute a 7x4 register tile: per-block FMA issues
// 2 waves x 1372 = 2744 (vs 4 x 784 with the old 4x4/196-thread tiling).
// ---------------------------------------------------------------------------
__global__ __launch_bounds__(128) void k_dw(const float* __restrict__ s,
                                            const float* __restrict__ wk,
                                            u16* __restrict__ xdw) {
    int bc = blockIdx.x, t = threadIdx.x;
    __shared__ float kw[49];
    __shared__ float sin_[62 * 62];
    {   // zero LDS with float4 stores (62*62 = 961 float4s)
        float4 z = {0.f, 0.f, 0.f, 0.f};
        float4* p = (float4*)sin_;
        for (int i = t; i < 961; i += 128) p[i] = z;
    }
    if (t < 49) kw[t] = wk[(size_t)bc * 49 + t];
    __syncthreads();
    const float4* src = (const float4*)(s + (size_t)bc * HWn);
    for (int i = t; i < HWn / 4; i += 128) {
        float4 v = src[i];
        int row = i / 14;
        int col = (i % 14) * 4;
        float* dst = &sin_[(row + 3) * 62 + col + 3];
        dst[0] = v.x; dst[1] = v.y; dst[2] = v.z; dst[3] = v.w;
    }
    __syncthreads();
    if (t < 112) {
        int r0 = (t / 14) * 7, c0 = (t % 14) * 4;
        float acc[7][4] = {};
        #pragma unroll
        for (int a = 0; a < 13; a++) {
            float row10[10];
            const float* rp = &sin_[(r0 + a) * 62 + c0];
            #pragma unroll
            for (int x = 0; x < 10; x++) row10[x] = rp[x];
            #pragma unroll
            for (int i = 0; i < 7; i++) {
                int ky = a - i;                       // compile-time after unroll
                if (ky >= 0 && ky < 7) {
                    #pragma unroll
                    for (int kx = 0; kx < 7; kx++) {
                        float wv = kw[ky * 7 + kx];
                        #pragma unroll
                        for (int j = 0; j < 4; j++) acc[i][j] += row10[j + kx] * wv;
                    }
                }
            }
        }
        u16* dst = xdw + (size_t)bc * HWn;
        #pragma unroll
        for (int i = 0; i < 7; i++) {
            u16 ov[4];
            #pragma unroll
            for (int j = 0; j < 4; j++) ov[j] = f2bf(gelu_fast(acc[i][j]));
            *(uint2*)(dst + (r0 + i) * 56 + c0) = *(const uint2*)ov;
        }
    }
}

// ---------------------------------------------------------------------------
// Kernel 4: pointwise GEMM, bf16 MFMA 16x16x32, fp32 out + bias.
// Per b: Out[256 d][3136 hw] = W[256][256] * X[256 c][3136 hw].
// Block tile 256d x 64hw (3136 = 49*64, X fetched exactly once from HBM),
// 4 waves each own a 64d stripe, BK=32, 8 k-steps. X staged transposed
// ([hw][c], stride 40, xor-swizzled c-groups) so both frags are ds_read_b128.
// ---------------------------------------------------------------------------
__global__ __launch_bounds__(256) void k_pw(const u16* __restrict__ xdw,
                                            const u16* __restrict__ wbf,
                                            const float* __restrict__ pw_b,
                                            float* __restrict__ out) {
    int tileHW = blockIdx.x;      // 0..48
    int b      = blockIdx.y;      // 0..31
    int t = threadIdx.x;
    int lane = t & 63;
    int wv = t >> 6;              // wave owns d stripe wv*64
    int hw0 = tileHW * 64;

    __shared__ __align__(16) u16 sA[256 * 40];   // [d][k]  stride 40
    __shared__ __align__(16) u16 sX[64 * 40];    // [hw][c] stride 40, swizzled

    floatx4 acc[4][4];
    #pragma unroll
    for (int mi = 0; mi < 4; mi++)
        #pragma unroll
        for (int ni = 0; ni < 4; ni++) acc[mi][ni] = (floatx4){0.f, 0.f, 0.f, 0.f};

    int arow = t >> 2;            // 0..63
    int akc  = t & 3;             // 0..3 (k-chunk of 8)
    int xc   = t >> 3;            // 0..31 (channel within k-step)
    int xhc  = t & 7;             // 0..7  (hw chunk of 8)
    int wgrp = (xc >> 3) ^ (xhc & 3);
    int scol = (wgrp << 3) | (xc & 7);

    const u16* Xbase = xdw + (size_t)b * Cn * HWn;
    int q = lane >> 4, l16 = lane & 15;

    for (int ks = 0; ks < 8; ks++) {
        int k0 = ks * 32;
        __syncthreads();
        // stage A (full 256-row W tile, 32 k)
        #pragma unroll
        for (int quarter = 0; quarter < 4; quarter++) {
            int dd = arow + quarter * 64;
            short8 v = *(const short8*)(wbf + dd * 256 + k0 + akc * 8);
            *(short8*)(&sA[dd * 40 + akc * 8]) = v;
        }
        // stage X transposed (64 hw x 32 c)
        {
            short8 v = *(const short8*)(Xbase + (size_t)(k0 + xc) * HWn + hw0 + xhc * 8);
            const u16* vp = (const u16*)&v;
            #pragma unroll
            for (int e = 0; e < 8; e++) sX[(xhc * 8 + e) * 40 + scol] = vp[e];
        }
        __syncthreads();
        short8 fa[4], fb[4];
        #pragma unroll
        for (int mi = 0; mi < 4; mi++) {
            int row = wv * 64 + mi * 16 + l16;
            fa[mi] = *(const short8*)(&sA[row * 40 + q * 8]);
        }
        #pragma unroll
        for (int ni = 0; ni < 4; ni++) {
            int hwRow = ni * 16 + l16;
            int rgrp = q ^ ((hwRow >> 3) & 3);
            fb[ni] = *(const short8*)(&sX[hwRow * 40 + rgrp * 8]);
        }
        #pragma unroll
        for (int mi = 0; mi < 4; mi++)
            #pragma unroll
            for (int ni = 0; ni < 4; ni++)
                acc[mi][ni] = __builtin_amdgcn_mfma_f32_16x16x32_bf16(fa[mi], fb[ni], acc[mi][ni], 0, 0, 0);
    }
    // epilogue: D row = q*4+reg (d), col = l16 (hw)
    #pragma unroll
    for (int mi = 0; mi < 4; mi++) {
        #pragma unroll
        for (int reg = 0; reg < 4; reg++) {
            int d = wv * 64 + mi * 16 + q * 4 + reg;
            float bias = pw_b[d];
            #pragma unroll
            for (int ni = 0; ni < 4; ni++) {
                int hw = hw0 + ni * 16 + l16;
                out[((size_t)b * Cn + d) * HWn + hw] = acc[mi][ni][reg] + bias;
            }
        }
    }
}

// ---------------------------------------------------------------------------
extern "C" void kernel_launch(void* const* d_in, const int* in_sizes, int n_in,
                              void* d_out, int out_size, void* d_ws, size_t ws_size,
                              hipStream_t stream) {
    const float* s          = (const float*)d_in[0];
    const float* r          = (const float*)d_in[1];
    const float* proj_w1    = (const float*)d_in[2];
    const float* proj_b1    = (const float*)d_in[3];
    const float* proj_w2    = (const float*)d_in[4];
    const float* proj_b2    = (const float*)d_in[5];
    const float* weight     = (const float*)d_in[6];
    const float* beta_scale = (const float*)d_in[7];
    const float* pw_w       = (const float*)d_in[8];
    const float* pw_b       = (const float*)d_in[9];
    float* out = (float*)d_out;

    char* ws = (char*)d_ws;
    float* pooled = (float*)(ws);                    //  32 KB
    u16*   wbf    = (u16*)(ws + 32768);              // 128 KB
    float* wk     = (float*)(ws + 163840);           // 1.57 MB
    u16*   xdw    = (u16*)(ws + 2097152);            // 51.4 MB

    k_pool<<<Bn * Cn + 64, 256, 0, stream>>>(r, pw_w, pooled, wbf);
    k_wgen<<<Bn, 256, 0, stream>>>(pooled, proj_w1, proj_b1, proj_w2, proj_b2,
                                   weight, beta_scale, wk);
    k_dw<<<Bn * Cn, 128, 0, stream>>>(s, wk, xdw);
    k_pw<<<dim3(49, Bn), 256, 0, stream>>>(xdw, wbf, pw_b, out);
}